// Round 9
// baseline (277.236 us; speedup 1.0000x reference)
//
#include <hip/hip_runtime.h>
#include <math.h>
#include <stdint.h>

#define NPART 16384
#define NSTEP 40
#define DIMA  22
#define OUT0_ELEMS 13434880
#define TRAJ_OFF   160

typedef __attribute__((ext_vector_type(8))) short short8;
typedef __attribute__((ext_vector_type(4))) float floatx4;
typedef __attribute__((ext_vector_type(4))) int   intx4;
typedef __attribute__((ext_vector_type(2))) int   intx2;

union V4 { intx4 i; short8 s; floatx4 f; };

// ---- LDS map (bytes): permuted-weight image (R8-validated) + biases/u ----
#define AIN_B   0           // 5 tiles x 1024
#define AH_B    5120        // 20 (l,mt) groups x (1024+1024+512)
#define AOUT_B  56320       // 2 groups x 2560
#define SB_B    62080       // f32: db_in[80] | db_h[320] | db_out padded[32] | u[160]
#define LDS_BYTES 64448
#define STAGE_DW  15360

__device__ __forceinline__ uint32_t bf16r(float x) {
    uint32_t u = __float_as_uint(x);
    u += 0x7FFFu + ((u >> 16) & 1u);   // RNE
    return u >> 16;
}
__device__ __forceinline__ uint32_t pk2(float a0, float a1) {
    return bf16r(a0) | (bf16r(a1) << 16);
}
#if defined(__has_builtin)
#if __has_builtin(__builtin_amdgcn_cvt_pk_bf16_f32)
#define HAS_PKCVT 1
#endif
#endif
__device__ __forceinline__ uint32_t pkq(float a0, float a1) {
#ifdef HAS_PKCVT
    auto r = __builtin_amdgcn_cvt_pk_bf16_f32(a0, a1);   // v_cvt_pk_bf16_f32 (RNE)
    uint32_t u; __builtin_memcpy(&u, &r, 4);
    return u;
#else
    return pk2(a0, a1);
#endif
}
__device__ __forceinline__ float fast_tanh(float x) {
    float e = __expf(2.0f * x);
    return 1.0f - 2.0f * __builtin_amdgcn_rcpf(e + 1.0f);
}

__global__ __launch_bounds__(256, 1) void sde_mfma(
    const float* __restrict__ z,      const float* __restrict__ t_arr,
    const float* __restrict__ Tx,     const float* __restrict__ noise,
    const float* __restrict__ dw_in,  const float* __restrict__ db_in,
    const float* __restrict__ dw_h,   const float* __restrict__ db_h,
    const float* __restrict__ dw_out, const float* __restrict__ db_out,
    const float* __restrict__ tw_in,  const float* __restrict__ tb_in,
    const float* __restrict__ tw_h,   const float* __restrict__ tb_h,
    const float* __restrict__ tw_out, const float* __restrict__ tb_out,
    float* __restrict__ out0,         float* __restrict__ traj)
{
    __shared__ __align__(16) uint8_t lds[LDS_BYTES];
    const int tid = threadIdx.x;

    // ---- stage PERMUTED bf16 weight image global -> LDS (R8-validated) ----
    //   A'[m][32kt+8q+2w+jj] = A[m][16(2kt+(w>>1)) + 4q + 2(w&1) + jj]
    for (int di = tid; di < STAGE_DW; di += 256) {
        uint32_t val = 0u;
        if (di < 1280) {                       // AIN: x = [y(20), u_t(4)]
            int r = di & 255, lane = r >> 2, w = r & 3;
            int m = lane & 15, q = lane >> 4, mt = di >> 8;
            int f = -1;
            if (w < 2)            f = 4 * q + 2 * w;
            else if (q == 0)      f = 16 + 2 * (w - 2);
            else if (q == 1)      f = 20 + 2 * (w - 2);
            if (f >= 0) val = pk2(dw_in[(mt * 16 + m) * 24 + f],
                                  dw_in[(mt * 16 + m) * 24 + f + 1]);
        } else if (di < 14080) {               // AH: 20 groups x 640 dw
            int q2 = di - 1280, g = q2 / 640, r = q2 % 640;
            int l = g / 5, mt = g % 5;
            int lane, f;
            if (r < 512) {
                int kt = r >> 8, rr = r & 255, w = rr & 3;
                lane = rr >> 2;
                f = 16 * (2 * kt + (w >> 1)) + 4 * (lane >> 4) + 2 * (w & 1);
            } else {
                int rr = r - 512, d = rr & 1;
                lane = rr >> 1;
                f = 64 + 4 * (lane >> 4) + 2 * d;
            }
            int m = lane & 15;
            val = pk2(dw_h[l * 6400 + (mt * 16 + m) * 80 + f],
                      dw_h[l * 6400 + (mt * 16 + m) * 80 + f + 1]);
        } else {                               // AOUT: 2 groups x 640 dw
            int q2 = di - 14080, mt = q2 / 640, r = q2 % 640;
            int lane, f;
            if (r < 512) {
                int kt = r >> 8, rr = r & 255, w = rr & 3;
                lane = rr >> 2;
                f = 16 * (2 * kt + (w >> 1)) + 4 * (lane >> 4) + 2 * (w & 1);
            } else {
                int rr = r - 512, d = rr & 1;
                lane = rr >> 1;
                f = 64 + 4 * (lane >> 4) + 2 * d;
            }
            int m = mt * 16 + (lane & 15);
            if (m < 20) val = pk2(dw_out[m * 80 + f], dw_out[m * 80 + f + 1]);
        }
        ((uint32_t*)lds)[di] = val;
    }
    {   // biases -> LDS (db_out zero-padded to 32 rows)
        float* sb = (float*)(lds + SB_B);
        for (int di = tid; di < 432; di += 256) {
            float v;
            if (di < 80)       v = db_in[di];
            else if (di < 400) v = db_h[di - 80];
            else               v = (di - 400 < 20) ? db_out[di - 400] : 0.f;
            sb[di] = v;
        }
        if (tid < NSTEP) {   // t-MLP u(t_i), fp32
            float ti = t_arr[tid];
            float hh[20], h2[20];
            #pragma unroll
            for (int j = 0; j < 20; j++) {
                float v = tw_in[j] * ti + tb_in[j];
                hh[j] = v > 0.f ? v : 0.f;
            }
            #pragma unroll
            for (int l = 0; l < 4; l++) {
                #pragma unroll
                for (int j = 0; j < 20; j++) {
                    float a = tb_h[l * 20 + j];
                    #pragma unroll
                    for (int k = 0; k < 20; k++) a += tw_h[(l * 20 + j) * 20 + k] * hh[k];
                    h2[j] = a > 0.f ? a : 0.f;
                }
                #pragma unroll
                for (int j = 0; j < 20; j++) hh[j] = h2[j];
            }
            #pragma unroll
            for (int c = 0; c < 4; c++) {
                float a = tb_out[c];
                #pragma unroll
                for (int k = 0; k < 20; k++) a += tw_out[c * 20 + k] * hh[k];
                sb[432 + tid * 4 + c] = a;
            }
        }
    }

    const int lane = tid & 63;
    const int n15  = lane & 15;
    const int quad = lane >> 4;
    const int wv   = tid >> 6;
    const int n    = blockIdx.x * 64 + wv * 16 + n15;
    const float Txb = Tx[blockIdx.x];
    const float dtv = t_arr[1] - t_arr[0];
    const float sdt = sqrtf(dtv);
    const float* sbf = (const float*)(lds + SB_B);
    __syncthreads();

    // persistent: input-layer A tiles (20 VGPR)
    V4 aIn[5];
    #pragma unroll
    for (int mt = 0; mt < 5; mt++)
        aIn[mt].i = *(const intx4*)(lds + AIN_B + mt * 1024 + lane * 16);

    // state in D-layout: y0[r] = y[quad*4+r]; y1[r] = y[16+quad*4+r] (quad0)
    float y0[4], y1[4] = {0.f, 0.f, 0.f, 0.f};
    {
        floatx4 zv = *(const floatx4*)(z + (size_t)n * 20 + quad * 4);
        #pragma unroll
        for (int r = 0; r < 4; r++) y0[r] = zv[r];
        *(floatx4*)(out0 + (size_t)n * 20 + quad * 4) = zv;
        if (quad == 0) {
            floatx4 z2 = *(const floatx4*)(z + (size_t)n * 20 + 16);
            #pragma unroll
            for (int r = 0; r < 4; r++) y1[r] = z2[r];
            *(floatx4*)(out0 + (size_t)n * 20 + 16) = z2;
            traj[n] = 0.f;
        }
    }

    double lq = 0.0;
    for (int i = 0; i < NSTEP; i++) {
        // prefetch noise (consumed at step bottom)
        size_t nbase = ((size_t)i * NPART + n) * DIMA;
        floatx4 dW0 = *(const floatx4*)(noise + nbase + quad * 4);
        floatx4 dW1 = {0.f, 0.f, 0.f, 0.f};
        if (quad == 0) dW1 = *(const floatx4*)(noise + nbase + 16);

        float ut0 = sbf[432 + i * 4 + 0] * Txb, ut1 = sbf[432 + i * 4 + 1] * Txb;
        float ut2 = sbf[432 + i * 4 + 2] * Txb, ut3 = sbf[432 + i * 4 + 3] * Txb;

        // ---- input B-frag: direct register pack (no cross-lane ops) ----
        V4 bin;
        bin.i[0] = pkq(y0[0], y0[1]);
        bin.i[1] = pkq(y0[2], y0[3]);
        if (quad == 0)      { bin.i[2] = pkq(y1[0], y1[1]); bin.i[3] = pkq(y1[2], y1[3]); }
        else if (quad == 1) { bin.i[2] = pkq(ut0, ut1);     bin.i[3] = pkq(ut2, ut3); }
        else                { bin.i[2] = 0;                 bin.i[3] = 0; }

        // ---- input layer ----
        floatx4 acc[5];
        #pragma unroll
        for (int mt = 0; mt < 5; mt++) {
            floatx4 c = *(const floatx4*)(sbf + mt * 16 + quad * 4);
            acc[mt] = __builtin_amdgcn_mfma_f32_16x16x32_bf16(aIn[mt].s, bin.s, c, 0, 0, 0);
        }
        // prefetch layer-0 A tiles + biases (hidden under relu/pack)
        V4 A0[5], A1[5]; intx2 A2[5]; floatx4 CB[5];
        #pragma unroll
        for (int mt = 0; mt < 5; mt++) {
            const uint8_t* grp = lds + AH_B + (size_t)mt * 2560;
            A0[mt].i = *(const intx4*)(grp + lane * 16);
            A1[mt].i = *(const intx4*)(grp + 1024 + lane * 16);
            A2[mt]   = *(const intx2*)(grp + 2048 + lane * 8);
            CB[mt]   = *(const floatx4*)(sbf + 80 + mt * 16 + quad * 4);
        }
        uint32_t pkA[5][2];
        #pragma unroll
        for (int mt = 0; mt < 5; mt++) {
            pkA[mt][0] = pkq(fmaxf(acc[mt][0], 0.f), fmaxf(acc[mt][1], 0.f));
            pkA[mt][1] = pkq(fmaxf(acc[mt][2], 0.f), fmaxf(acc[mt][3], 0.f));
        }

        // ---- 4 hidden tanh layers, software-pipelined A loads ----
        V4 O0[2], O1[2]; intx2 O2[2]; floatx4 OB[2];
        #pragma unroll
        for (int l = 0; l < 4; l++) {
            V4 b0, b1, b2;
            b0.i = (intx4){(int)pkA[0][0], (int)pkA[0][1], (int)pkA[1][0], (int)pkA[1][1]};
            b1.i = (intx4){(int)pkA[2][0], (int)pkA[2][1], (int)pkA[3][0], (int)pkA[3][1]};
            b2.i = (intx4){(int)pkA[4][0], (int)pkA[4][1], 0, 0};
            #pragma unroll
            for (int mt = 0; mt < 5; mt++) {
                V4 a2f; a2f.i = (intx4){A2[mt][0], A2[mt][1], 0, 0};
                floatx4 c = CB[mt];
                c = __builtin_amdgcn_mfma_f32_16x16x32_bf16(A0[mt].s, b0.s, c, 0, 0, 0);
                c = __builtin_amdgcn_mfma_f32_16x16x32_bf16(A1[mt].s, b1.s, c, 0, 0, 0);
                acc[mt] = __builtin_amdgcn_mfma_f32_16x16x32_bf16(a2f.s, b2.s, c, 0, 0, 0);
            }
            if (l < 3) {   // prefetch next layer (hidden under tanh)
                #pragma unroll
                for (int mt = 0; mt < 5; mt++) {
                    const uint8_t* grp = lds + AH_B + (size_t)((l + 1) * 5 + mt) * 2560;
                    A0[mt].i = *(const intx4*)(grp + lane * 16);
                    A1[mt].i = *(const intx4*)(grp + 1024 + lane * 16);
                    A2[mt]   = *(const intx2*)(grp + 2048 + lane * 8);
                    CB[mt]   = *(const floatx4*)(sbf + 80 + (l + 1) * 80 + mt * 16 + quad * 4);
                }
            } else {       // prefetch output-layer tiles
                #pragma unroll
                for (int mt = 0; mt < 2; mt++) {
                    const uint8_t* grp = lds + AOUT_B + (size_t)mt * 2560;
                    O0[mt].i = *(const intx4*)(grp + lane * 16);
                    O1[mt].i = *(const intx4*)(grp + 1024 + lane * 16);
                    O2[mt]   = *(const intx2*)(grp + 2048 + lane * 8);
                    OB[mt]   = *(const floatx4*)(sbf + 400 + mt * 16 + quad * 4);
                }
            }
            #pragma unroll
            for (int mt = 0; mt < 5; mt++) {
                pkA[mt][0] = pkq(fast_tanh(acc[mt][0]), fast_tanh(acc[mt][1]));
                pkA[mt][1] = pkq(fast_tanh(acc[mt][2]), fast_tanh(acc[mt][3]));
            }
        }

        // ---- output layer (M=20 padded to 32; OB rows>=20 are zero) ----
        V4 b0, b1, b2;
        b0.i = (intx4){(int)pkA[0][0], (int)pkA[0][1], (int)pkA[1][0], (int)pkA[1][1]};
        b1.i = (intx4){(int)pkA[2][0], (int)pkA[2][1], (int)pkA[3][0], (int)pkA[3][1]};
        b2.i = (intx4){(int)pkA[4][0], (int)pkA[4][1], 0, 0};
        floatx4 oacc[2];
        #pragma unroll
        for (int mt = 0; mt < 2; mt++) {
            V4 a2f; a2f.i = (intx4){O2[mt][0], O2[mt][1], 0, 0};
            floatx4 c = OB[mt];
            c = __builtin_amdgcn_mfma_f32_16x16x32_bf16(O0[mt].s, b0.s, c, 0, 0, 0);
            c = __builtin_amdgcn_mfma_f32_16x16x32_bf16(O1[mt].s, b1.s, c, 0, 0, 0);
            oacc[mt] = __builtin_amdgcn_mfma_f32_16x16x32_bf16(a2f.s, b2.s, c, 0, 0, 0);
        }

        // ---- SDE update + logqp ----
        float part = 0.f;
        size_t obase = ((size_t)(i + 1) * NPART + n) * 20;
        floatx4 st;
        #pragma unroll
        for (int r = 0; r < 4; r++) {
            float o = oacc[0][r];
            float y = y0[r];
            float f = o + y;                 // f = mlp - h, h = -y
            float uu = 2.f * o + 4.f * y;    // (f - h)/sigma
            part += uu * uu;
            y0[r] = y + f * dtv + (0.5f * sdt) * dW0[r];
            st[r] = y0[r];
        }
        *(floatx4*)(out0 + obase + quad * 4) = st;
        if (quad == 0) {
            floatx4 st2;
            #pragma unroll
            for (int r = 0; r < 4; r++) {
                float o = oacc[1][r];
                float y = y1[r];
                float f = o + y;
                float uu = 2.f * o + 4.f * y;
                part += uu * uu;
                y1[r] = y + f * dtv + (0.5f * sdt) * dW1[r];
                st2[r] = y1[r];
            }
            *(floatx4*)(out0 + obase + 16) = st2;
        }
        part += __shfl_xor(part, 16);
        part += __shfl_xor(part, 32);
        lq += 0.5 * (double)part * (double)dtv;
        if (quad == 0) traj[(size_t)(i + 1) * NPART + n] = (float)lq;
    }
}

// out1[i] = logqp trajectory at flat (t*N+n) index 41*i + 40
__global__ void gather_logqp(const float* __restrict__ traj, float* __restrict__ out1) {
    int i = blockIdx.x * 256 + threadIdx.x;
    if (i < NPART) out1[i] = traj[(size_t)41 * i + 40];
}

extern "C" void kernel_launch(void* const* d_in, const int* in_sizes, int n_in,
                              void* d_out, int out_size, void* d_ws, size_t ws_size,
                              hipStream_t stream) {
    const float* z      = (const float*)d_in[0];
    const float* t_arr  = (const float*)d_in[1];
    const float* Tx     = (const float*)d_in[2];
    const float* noise  = (const float*)d_in[3];
    const float* tw_in  = (const float*)d_in[4];
    const float* tb_in  = (const float*)d_in[5];
    const float* tw_h   = (const float*)d_in[6];
    const float* tb_h   = (const float*)d_in[7];
    const float* tw_out = (const float*)d_in[8];
    const float* tb_out = (const float*)d_in[9];
    const float* dw_in  = (const float*)d_in[10];
    const float* db_in  = (const float*)d_in[11];
    const float* dw_h   = (const float*)d_in[12];
    const float* db_h   = (const float*)d_in[13];
    const float* dw_out = (const float*)d_in[14];
    const float* db_out = (const float*)d_in[15];

    float* wsf  = (float*)d_ws;
    float* traj = wsf + TRAJ_OFF;
    float* out0 = (float*)d_out;
    float* out1 = out0 + OUT0_ELEMS;

    hipLaunchKernelGGL(sde_mfma, dim3(256), dim3(256), 0, stream,
                       z, t_arr, Tx, noise, dw_in, db_in, dw_h, db_h,
                       dw_out, db_out, tw_in, tb_in, tw_h, tb_h, tw_out, tb_out,
                       out0, traj);
    hipLaunchKernelGGL(gather_logqp, dim3(64), dim3(256), 0, stream, traj, out1);
}